// Round 4
// baseline (208.514 us; speedup 1.0000x reference)
//
#include <hip/hip_runtime.h>
#include <math.h>

// ---------------------------------------------------------------------------
// YOLO loss, forward only — single fused kernel, last-block-done reduction.
//   d_in[0] l_prediction (32,3,13,13,85) f32
//   d_in[1] m_prediction (32,3,26,26,85) f32
//   d_in[2] s_prediction (32,3,52,52,85) f32
//   d_in[3] targets      (32,50,5)       f32
// Output: 1 float scalar.
//
// Grid (46, 32). Per image b:
//   blocks 0..41  : per-cell conf phase (scan 50 LDS keys, conf BCE only).
//   blocks 42..45 : wave-per-target phase (coalesced 85-ch read, class BCE,
//                   CIoU; last-write-wins dedup via ballot).
// Epilogue: block partial -> agent-scope release store; acq-rel counter;
// the last block gathers 1472 partials (agent-scope loads, safe across
// non-coherent XCD L2s) and writes out[0]. Counter zeroed by memsetAsync.
// ---------------------------------------------------------------------------

#define NBLK_X 46
#define NBLK_TOT (46 * 32)

__constant__ float c_anch[9][2] = {
    {10.f, 13.f},  {16.f, 30.f},   {33.f, 23.f},
    {30.f, 61.f},  {62.f, 45.f},   {59.f, 119.f},
    {116.f, 90.f}, {156.f, 198.f}, {373.f, 326.f}};

__device__ __forceinline__ float sp_fast(float x) {
  return fmaxf(x, 0.f) + __logf(1.f + __expf(-fabsf(x)));
}
__device__ __forceinline__ float sigmoid_fast(float x) {
  return 1.f / (1.f + __expf(-x));
}

__device__ __forceinline__ float ciou_f(float px, float py, float pw, float ph,
                                        float gx, float gy, float gw, float gh) {
  float p_x1 = px - pw * 0.5f, p_x2 = px + pw * 0.5f;
  float p_y1 = py - ph * 0.5f, p_y2 = py + ph * 0.5f;
  float g_x1 = gx - gw * 0.5f, g_x2 = gx + gw * 0.5f;
  float g_y1 = gy - gh * 0.5f, g_y2 = gy + gh * 0.5f;
  float iw = fmaxf(fminf(p_x2, g_x2) - fmaxf(p_x1, g_x1), 0.f);
  float ih = fmaxf(fminf(p_y2, g_y2) - fmaxf(p_y1, g_y1), 0.f);
  float inter = iw * ih;
  float a1 = pw * ph, a2 = gw * gh;
  float iou = inter / (a1 + a2 - inter + 1e-6f);
  float dx = gx - px, dy = gy - py;
  float d2 = dx * dx + dy * dy;
  float cw = fmaxf(p_x2, g_x2) - fminf(p_x1, g_x1);
  float chh = fmaxf(p_y2, g_y2) - fminf(p_y1, g_y1);
  float c2 = cw * cw + chh * chh + 1e-6f;
  float dv = atanf(pw / (ph + 1e-6f)) - atanf(gw / (gh + 1e-6f));
  float v = 0.4052847346f * dv * dv;  // 4/pi^2
  float alpha = v / (1.f - iou + v + 1e-6f);
  return iou - d2 / c2 - alpha * v;
}

// key = gi | gj<<6 | bn<<12 | ign<<14 (low 17 bits); grid-unit coords out.
__device__ __forceinline__ int digest(float cx, float cy, float w, float h,
                                      int s, float* gx, float* gy, float* gw,
                                      float* gh) {
  float Wf = (float)(13 << s);
  float x = cx * Wf, y = cy * Wf, ww = w * Wf, hh = h * Wf;
  float areag = ww * hh;
  float best = -1.f;
  int bn = 0, ign = 0;
#pragma unroll
  for (int k = 0; k < 3; ++k) {
    float aw = c_anch[(2 - s) * 3 + k][0] * (1.f / 416.f);
    float ah = c_anch[(2 - s) * 3 + k][1] * (1.f / 416.f);
    float inter = fminf(ww, aw) * fminf(hh, ah);
    float iou = inter / (areag + aw * ah - inter + 1e-6f);
    if (iou > best) { best = iou; bn = k; }  // first-max == jnp.argmax
    if (iou > 0.5f) ign |= (1 << k);
  }
  int gi = (int)floorf(x);
  int gj = (int)floorf(y);
  *gx = x; *gy = y; *gw = ww; *gh = hh;
  return gi | (gj << 6) | (bn << 12) | (ign << 14);
}

__global__ __launch_bounds__(256) void yolo_fused(
    const float* __restrict__ predL, const float* __restrict__ predM,
    const float* __restrict__ predS, const float* __restrict__ targets,
    float* __restrict__ partial, int* __restrict__ counter,
    float* __restrict__ out) {
  __shared__ int skey[150];
  __shared__ float wsum[4];
  __shared__ int slast;
  const int b = blockIdx.y;
  const int t = threadIdx.x;
  const int lane = t & 63, wid = t >> 6;
  float local = 0.f;

  if (blockIdx.x < 42) {
    // ---------------- per-cell conf phase ----------------
    if (t < 150) {
      int s = t / 50;
      int n = t - s * 50;
      const float* tg = targets + (b * 50 + n) * 5;
      float gx, gy, gw, gh;
      skey[t] = digest(tg[1], tg[2], tg[3], tg[4], s, &gx, &gy, &gw, &gh);
    }
    __syncthreads();

    int cell = blockIdx.x * 256 + t;
    if (cell < 10647) {
      int s, c;
      const float* pred;
      if (cell < 507)       { s = 0; c = cell;        pred = predL; }
      else if (cell < 2535) { s = 1; c = cell - 507;  pred = predM; }
      else                  { s = 2; c = cell - 2535; pred = predS; }
      const int W = 13 << s;
      const int HW = W * W;
      int a = (c >> (2 * s)) / 169;  // == c / HW
      int rem = c - a * HW;
      int j = (rem >> s) / 13;       // == rem / W
      int i = rem - j * W;
      float conf = pred[(size_t)((b * 3 + a) * HW + rem) * 85 + 4];

      int probe = i | (j << 6);
      bool masked = false, ign = false;
      const int base = s * 50;
      for (int n = 0; n < 50; ++n) {  // LDS broadcast reads
        int k = skey[base + n];
        if ((k & 0xFFF) == probe) {
          masked = masked || (((k >> 12) & 3) == a);
          ign = ign || (((k >> (14 + a)) & 1) != 0);
        }
      }
      float BAL = (s == 0) ? 0.4f : ((s == 1) ? 1.0f : 4.0f);
      if (masked)
        local = 5.f * BAL * (sp_fast(conf) - conf);  // obj conf (OBJ_RATIO=5)
      else if (!ign)
        local = 5.f * BAL * sp_fast(conf);           // noobj conf
    }
  } else {
    // ---------------- wave-per-target phase ----------------
    const int wglob = (blockIdx.x - 42) * 4 + wid;  // 16 waves/image
    float cls = 0.f, cx = 0.f, cy = 0.f, w = 0.f, h = 0.f;
    if (lane < 50) {
      const float* tg = targets + (b * 50 + lane) * 5;
      cls = tg[0]; cx = tg[1]; cy = tg[2]; w = tg[3]; h = tg[4];
    }
    for (int task = wglob; task < 150; task += 16) {
      int s = task / 50;  // wave-uniform
      int n = task - s * 50;
      int key = 0x7FFFFFFF;
      float gx = 0.f, gy = 0.f, gw = 0.f, gh = 0.f;
      if (lane < 50) key = digest(cx, cy, w, h, s, &gx, &gy, &gw, &gh);
      int key_n = __shfl(key, n, 64);
      // last-write-wins dedup: n wins iff no later n' hits the same cell
      unsigned long long later = __ballot(
          lane < 50 && lane > n && ((key ^ key_n) & 0x3FFF) == 0);
      if (later == 0ULL) {
        float gxn = __shfl(gx, n, 64), gyn = __shfl(gy, n, 64);
        float gwn = __shfl(gw, n, 64), ghn = __shfl(gh, n, 64);
        float blsn = 2.f - __shfl(w, n, 64) * __shfl(h, n, 64);
        int clsn = (int)__shfl(cls, n, 64);
        int gi = key_n & 63, gj = (key_n >> 6) & 63, a = (key_n >> 12) & 3;
        const float* pred = (s == 0) ? predL : ((s == 1) ? predM : predS);
        const int W = 13 << s;
        const int HW = W * W;
        const float* pc = pred + (size_t)((b * 3 + a) * HW + gj * W + gi) * 85;
        float c1 = pc[lane];                          // coalesced: lane==ch
        float c2 = (lane < 21) ? pc[64 + lane] : 0.f;
        float v = (lane >= 5) ? sp_fast(c1) : 0.f;    // class BCE partials
        if (lane < 21) v += sp_fast(c2);
#pragma unroll
        for (int off = 32; off > 0; off >>= 1) v += __shfl_down(v, off, 64);
        int ch = 5 + clsn;
        float pch = (ch < 64) ? __shfl(c1, ch, 64) : __shfl(c2, ch - 64, 64);
        float p0 = __shfl(c1, 0, 64), p1 = __shfl(c1, 1, 64);
        float p2 = __shfl(c1, 2, 64), p3 = __shfl(c1, 3, 64);
        if (lane == 0) {
          float aw = c_anch[(2 - s) * 3 + a][0] * (1.f / 416.f);
          float ah = c_anch[(2 - s) * 3 + a][1] * (1.f / 416.f);
          float px = sigmoid_fast(p0) + (float)gi;
          float py = sigmoid_fast(p1) + (float)gj;
          float pw = __expf(p2) * aw;
          float ph = __expf(p3) * ah;
          float ci = ciou_f(px, py, pw, ph, gxn, gyn, gwn, ghn);
          local += (v - pch) + 0.05f * (1.f - ci) * blsn;  // CLS_RATIO=1
        }
      }
    }
  }

  // block reduction: wave(64) shuffle, then 4-wave LDS
#pragma unroll
  for (int off = 32; off > 0; off >>= 1) local += __shfl_down(local, off, 64);
  if (lane == 0) wsum[wid] = local;
  __syncthreads();

  // last-block-done final reduction (agent scope: safe across XCD L2s)
  if (t == 0) {
    float p = wsum[0] + wsum[1] + wsum[2] + wsum[3];
    __hip_atomic_store(&partial[b * NBLK_X + blockIdx.x], p, __ATOMIC_RELEASE,
                       __HIP_MEMORY_SCOPE_AGENT);
    int old = __hip_atomic_fetch_add(counter, 1, __ATOMIC_ACQ_REL,
                                     __HIP_MEMORY_SCOPE_AGENT);
    slast = (old == NBLK_TOT - 1) ? 1 : 0;
  }
  __syncthreads();
  if (slast) {
    float v = 0.f;
    for (int idx = t; idx < NBLK_TOT; idx += 256)
      v += __hip_atomic_load(&partial[idx], __ATOMIC_RELAXED,
                             __HIP_MEMORY_SCOPE_AGENT);
#pragma unroll
    for (int off = 32; off > 0; off >>= 1) v += __shfl_down(v, off, 64);
    if (lane == 0) wsum[wid] = v;
    __syncthreads();
    if (t == 0) out[0] = wsum[0] + wsum[1] + wsum[2] + wsum[3];
  }
}

extern "C" void kernel_launch(void* const* d_in, const int* in_sizes, int n_in,
                              void* d_out, int out_size, void* d_ws,
                              size_t ws_size, hipStream_t stream) {
  const float* l = (const float*)d_in[0];
  const float* m = (const float*)d_in[1];
  const float* s = (const float*)d_in[2];
  const float* tg = (const float*)d_in[3];
  float* out = (float*)d_out;
  int* counter = (int*)d_ws;                       // 4 B flag
  float* partial = (float*)((char*)d_ws + 256);    // 1472 floats

  hipMemsetAsync(counter, 0, sizeof(int), stream);  // graph-capturable
  hipLaunchKernelGGL(yolo_fused, dim3(NBLK_X, 32), dim3(256), 0, stream, l, m,
                     s, tg, partial, counter, out);
}

// Round 5
// 158.275 us; speedup vs baseline: 1.3174x; 1.3174x over previous
//
#include <hip/hip_runtime.h>
#include <math.h>

// ---------------------------------------------------------------------------
// YOLO loss, forward only — fused, shape-split version (R3 structure).
//   d_in[0] l_prediction (32,3,13,13,85) f32
//   d_in[1] m_prediction (32,3,26,26,85) f32
//   d_in[2] s_prediction (32,3,52,52,85) f32
//   d_in[3] targets      (32,50,5)       f32
// Output: 1 float scalar.
//
// Grid (46, 32). Per image b:
//   blocks 0..41  : per-cell conf phase (scan 50 LDS keys, conf BCE only).
//   blocks 42..45 : wave-per-target phase (coalesced 85-ch read, class BCE,
//                   CIoU; last-write-wins dedup via ballot).
// Block partials -> d_ws (plain stores), tiny reduce kernel -> out[0].
// NOTE (R4 lesson): do NOT replace the reduce launch with a last-block-done
// agent-scope atomic epilogue — per-block acq-rel cache maintenance across
// the 8 non-coherent XCD L2s cost ~75 us, far more than one launch gap.
// ---------------------------------------------------------------------------

__constant__ float c_anch[9][2] = {
    {10.f, 13.f},  {16.f, 30.f},   {33.f, 23.f},
    {30.f, 61.f},  {62.f, 45.f},   {59.f, 119.f},
    {116.f, 90.f}, {156.f, 198.f}, {373.f, 326.f}};

__device__ __forceinline__ float sp_fast(float x) {
  return fmaxf(x, 0.f) + __logf(1.f + __expf(-fabsf(x)));
}
__device__ __forceinline__ float sigmoid_fast(float x) {
  return 1.f / (1.f + __expf(-x));
}

__device__ __forceinline__ float ciou_f(float px, float py, float pw, float ph,
                                        float gx, float gy, float gw, float gh) {
  float p_x1 = px - pw * 0.5f, p_x2 = px + pw * 0.5f;
  float p_y1 = py - ph * 0.5f, p_y2 = py + ph * 0.5f;
  float g_x1 = gx - gw * 0.5f, g_x2 = gx + gw * 0.5f;
  float g_y1 = gy - gh * 0.5f, g_y2 = gy + gh * 0.5f;
  float iw = fmaxf(fminf(p_x2, g_x2) - fmaxf(p_x1, g_x1), 0.f);
  float ih = fmaxf(fminf(p_y2, g_y2) - fmaxf(p_y1, g_y1), 0.f);
  float inter = iw * ih;
  float a1 = pw * ph, a2 = gw * gh;
  float iou = inter / (a1 + a2 - inter + 1e-6f);
  float dx = gx - px, dy = gy - py;
  float d2 = dx * dx + dy * dy;
  float cw = fmaxf(p_x2, g_x2) - fminf(p_x1, g_x1);
  float chh = fmaxf(p_y2, g_y2) - fminf(p_y1, g_y1);
  float c2 = cw * cw + chh * chh + 1e-6f;
  float dv = atanf(pw / (ph + 1e-6f)) - atanf(gw / (gh + 1e-6f));
  float v = 0.4052847346f * dv * dv;  // 4/pi^2
  float alpha = v / (1.f - iou + v + 1e-6f);
  return iou - d2 / c2 - alpha * v;
}

// key = gi | gj<<6 | bn<<12 | ign<<14 (low 17 bits); grid-unit coords out.
__device__ __forceinline__ int digest(float cx, float cy, float w, float h,
                                      int s, float* gx, float* gy, float* gw,
                                      float* gh) {
  float Wf = (float)(13 << s);
  float x = cx * Wf, y = cy * Wf, ww = w * Wf, hh = h * Wf;
  float areag = ww * hh;
  float best = -1.f;
  int bn = 0, ign = 0;
#pragma unroll
  for (int k = 0; k < 3; ++k) {
    float aw = c_anch[(2 - s) * 3 + k][0] * (1.f / 416.f);
    float ah = c_anch[(2 - s) * 3 + k][1] * (1.f / 416.f);
    float inter = fminf(ww, aw) * fminf(hh, ah);
    float iou = inter / (areag + aw * ah - inter + 1e-6f);
    if (iou > best) { best = iou; bn = k; }  // first-max == jnp.argmax
    if (iou > 0.5f) ign |= (1 << k);
  }
  int gi = (int)floorf(x);
  int gj = (int)floorf(y);
  *gx = x; *gy = y; *gw = ww; *gh = hh;
  return gi | (gj << 6) | (bn << 12) | (ign << 14);
}

// cells/image: s0 507, s1 2028, s2 8112 => 10647; 42 cell-blocks + 4 tgt-blocks
__global__ __launch_bounds__(256) void yolo_fused(
    const float* __restrict__ predL, const float* __restrict__ predM,
    const float* __restrict__ predS, const float* __restrict__ targets,
    float* __restrict__ partial) {
  __shared__ int skey[150];
  __shared__ float wsum[4];
  const int b = blockIdx.y;
  const int t = threadIdx.x;
  const int lane = t & 63, wid = t >> 6;
  float local = 0.f;

  if (blockIdx.x < 42) {
    // ---------------- per-cell conf phase ----------------
    if (t < 150) {
      int s = t / 50;
      int n = t - s * 50;
      const float* tg = targets + (b * 50 + n) * 5;
      float gx, gy, gw, gh;
      skey[t] = digest(tg[1], tg[2], tg[3], tg[4], s, &gx, &gy, &gw, &gh);
    }
    __syncthreads();

    int cell = blockIdx.x * 256 + t;
    if (cell < 10647) {
      int s, c;
      const float* pred;
      if (cell < 507)       { s = 0; c = cell;        pred = predL; }
      else if (cell < 2535) { s = 1; c = cell - 507;  pred = predM; }
      else                  { s = 2; c = cell - 2535; pred = predS; }
      const int W = 13 << s;
      const int HW = W * W;
      int a = (c >> (2 * s)) / 169;  // == c / HW
      int rem = c - a * HW;
      int j = (rem >> s) / 13;       // == rem / W
      int i = rem - j * W;
      float conf = pred[(size_t)((b * 3 + a) * HW + rem) * 85 + 4];

      int probe = i | (j << 6);
      bool masked = false, ign = false;
      const int base = s * 50;
      for (int n = 0; n < 50; ++n) {  // LDS broadcast reads
        int k = skey[base + n];
        if ((k & 0xFFF) == probe) {
          masked = masked || (((k >> 12) & 3) == a);
          ign = ign || (((k >> (14 + a)) & 1) != 0);
        }
      }
      float BAL = (s == 0) ? 0.4f : ((s == 1) ? 1.0f : 4.0f);
      if (masked)
        local = 5.f * BAL * (sp_fast(conf) - conf);  // obj conf (OBJ_RATIO=5)
      else if (!ign)
        local = 5.f * BAL * sp_fast(conf);           // noobj conf
    }
  } else {
    // ---------------- wave-per-target phase ----------------
    const int wglob = (blockIdx.x - 42) * 4 + wid;  // 16 waves/image
    float cls = 0.f, cx = 0.f, cy = 0.f, w = 0.f, h = 0.f;
    if (lane < 50) {
      const float* tg = targets + (b * 50 + lane) * 5;
      cls = tg[0]; cx = tg[1]; cy = tg[2]; w = tg[3]; h = tg[4];
    }
    for (int task = wglob; task < 150; task += 16) {
      int s = task / 50;  // wave-uniform
      int n = task - s * 50;
      int key = 0x7FFFFFFF;
      float gx = 0.f, gy = 0.f, gw = 0.f, gh = 0.f;
      if (lane < 50) key = digest(cx, cy, w, h, s, &gx, &gy, &gw, &gh);
      int key_n = __shfl(key, n, 64);
      // last-write-wins dedup: n wins iff no later n' hits the same cell
      unsigned long long later = __ballot(
          lane < 50 && lane > n && ((key ^ key_n) & 0x3FFF) == 0);
      if (later == 0ULL) {
        float gxn = __shfl(gx, n, 64), gyn = __shfl(gy, n, 64);
        float gwn = __shfl(gw, n, 64), ghn = __shfl(gh, n, 64);
        float blsn = 2.f - __shfl(w, n, 64) * __shfl(h, n, 64);
        int clsn = (int)__shfl(cls, n, 64);
        int gi = key_n & 63, gj = (key_n >> 6) & 63, a = (key_n >> 12) & 3;
        const float* pred = (s == 0) ? predL : ((s == 1) ? predM : predS);
        const int W = 13 << s;
        const int HW = W * W;
        const float* pc = pred + (size_t)((b * 3 + a) * HW + gj * W + gi) * 85;
        float c1 = pc[lane];                          // coalesced: lane==ch
        float c2 = (lane < 21) ? pc[64 + lane] : 0.f;
        float v = (lane >= 5) ? sp_fast(c1) : 0.f;    // class BCE partials
        if (lane < 21) v += sp_fast(c2);
#pragma unroll
        for (int off = 32; off > 0; off >>= 1) v += __shfl_down(v, off, 64);
        int ch = 5 + clsn;
        float pch = (ch < 64) ? __shfl(c1, ch, 64) : __shfl(c2, ch - 64, 64);
        float p0 = __shfl(c1, 0, 64), p1 = __shfl(c1, 1, 64);
        float p2 = __shfl(c1, 2, 64), p3 = __shfl(c1, 3, 64);
        if (lane == 0) {
          float aw = c_anch[(2 - s) * 3 + a][0] * (1.f / 416.f);
          float ah = c_anch[(2 - s) * 3 + a][1] * (1.f / 416.f);
          float px = sigmoid_fast(p0) + (float)gi;
          float py = sigmoid_fast(p1) + (float)gj;
          float pw = __expf(p2) * aw;
          float ph = __expf(p3) * ah;
          float ci = ciou_f(px, py, pw, ph, gxn, gyn, gwn, ghn);
          local += (v - pch) + 0.05f * (1.f - ci) * blsn;  // CLS_RATIO=1
        }
      }
    }
    __syncthreads();  // match the cell-branch barrier (block-uniform branch)
  }

  // wave(64) shuffle reduce, then 4-wave LDS reduce, one store per block
#pragma unroll
  for (int off = 32; off > 0; off >>= 1) local += __shfl_down(local, off, 64);
  if (lane == 0) wsum[wid] = local;
  __syncthreads();
  if (t == 0)
    partial[b * gridDim.x + blockIdx.x] = wsum[0] + wsum[1] + wsum[2] + wsum[3];
}

__global__ __launch_bounds__(256) void reduce_kernel(
    const float* __restrict__ partial, float* __restrict__ out, int n) {
  __shared__ float wsum[4];
  float v = 0.f;
  for (int idx = threadIdx.x; idx < n; idx += 256) v += partial[idx];
#pragma unroll
  for (int off = 32; off > 0; off >>= 1) v += __shfl_down(v, off, 64);
  int lane = threadIdx.x & 63, wid = threadIdx.x >> 6;
  if (lane == 0) wsum[wid] = v;
  __syncthreads();
  if (threadIdx.x == 0) out[0] = wsum[0] + wsum[1] + wsum[2] + wsum[3];
}

extern "C" void kernel_launch(void* const* d_in, const int* in_sizes, int n_in,
                              void* d_out, int out_size, void* d_ws,
                              size_t ws_size, hipStream_t stream) {
  const float* l = (const float*)d_in[0];
  const float* m = (const float*)d_in[1];
  const float* s = (const float*)d_in[2];
  const float* tg = (const float*)d_in[3];
  float* out = (float*)d_out;
  float* partial = (float*)d_ws;  // 46*32 = 1472 floats

  hipLaunchKernelGGL(yolo_fused, dim3(46, 32), dim3(256), 0, stream, l, m, s,
                     tg, partial);
  hipLaunchKernelGGL(reduce_kernel, dim3(1), dim3(256), 0, stream, partial,
                     out, 46 * 32);
}